// Round 3
// baseline (195.368 us; speedup 1.0000x reference)
//
#include <hip/hip_runtime.h>

typedef __bf16 bf16x8 __attribute__((ext_vector_type(8)));
typedef float f32x4 __attribute__((ext_vector_type(4)));

#define NEG_SLOPE 0.01f
#define BN_EPS 1e-5f

static __device__ __forceinline__ unsigned short f2bf(float f) {
    unsigned u = __builtin_bit_cast(unsigned, f);
    unsigned r = (u + 0x7fffu + ((u >> 16) & 1u)) >> 16;
    return (unsigned short)r;
}

// ---- convert ef, W_edge0, W_edge1 to bf16 in one launch ----
__global__ __launch_bounds__(256) void cvt3(const float* __restrict__ a, int na4,
                                            const float* __restrict__ b, int nb4,
                                            const float* __restrict__ c, int nc4,
                                            unsigned short* __restrict__ oa,
                                            unsigned short* __restrict__ ob,
                                            unsigned short* __restrict__ oc) {
    int idx = blockIdx.x * 256 + threadIdx.x;
    const float* in; unsigned short* outp; int i;
    if (idx < na4)            { in = a; outp = oa; i = idx; }
    else if (idx < na4 + nb4) { in = b; outp = ob; i = idx - na4; }
    else                      { in = c; outp = oc; i = idx - na4 - nb4; }
    const f32x4 v = *reinterpret_cast<const f32x4*>(in + (size_t)i * 4);
    ushort4 u;
    u.x = f2bf(v.x); u.y = f2bf(v.y); u.z = f2bf(v.z); u.w = f2bf(v.w);
    *reinterpret_cast<ushort4*>(outp + (size_t)i * 4) = u;
}

// ---- root + node-bias: y=0: aggr = x@W_root + b_root ; y=1: NB = x@be_rs ----
__global__ __launch_bounds__(256) void node_mm2(const float* __restrict__ x,
                                                const float* __restrict__ Wr,
                                                const float* __restrict__ br,
                                                float* __restrict__ aggr,
                                                const float* __restrict__ be,
                                                float* __restrict__ NB) {
    const float* M; const float* bias; float* out;
    if (blockIdx.y == 0) { M = Wr; bias = br; out = aggr; }
    else                 { M = be; bias = nullptr; out = NB; }
    __shared__ float Ml[64][64];
    __shared__ float xl[64][64];
    const int tid = threadIdx.x;
    const int n0 = blockIdx.x * 64;
    for (int f = tid; f < 1024; f += 256) {
        int r = f >> 4, c = f & 15;
        *reinterpret_cast<float4*>(&Ml[r][c * 4]) =
            *reinterpret_cast<const float4*>(M + (size_t)r * 64 + c * 4);
        *reinterpret_cast<float4*>(&xl[r][c * 4]) =
            *reinterpret_cast<const float4*>(x + (size_t)(n0 + r) * 64 + c * 4);
    }
    __syncthreads();
    const int o = tid & 63, g = tid >> 6;
    float acc[16] = {};
    for (int i4 = 0; i4 < 16; ++i4) {
        float m0 = Ml[4 * i4 + 0][o], m1 = Ml[4 * i4 + 1][o];
        float m2 = Ml[4 * i4 + 2][o], m3 = Ml[4 * i4 + 3][o];
#pragma unroll
        for (int k = 0; k < 16; ++k) {
            const f32x4 xv = *reinterpret_cast<const f32x4*>(&xl[g + 4 * k][4 * i4]);
            acc[k] += xv.x * m0 + xv.y * m1 + xv.z * m2 + xv.w * m3;
        }
    }
    const float b = bias ? bias[o] : 0.f;
#pragma unroll
    for (int k = 0; k < 16; ++k)
        out[(size_t)(n0 + g + 4 * k) * 64 + o] = acc[k] + b;
}

// ---- fused NNConv message: per block 64 edges, full K=4096 ----
// D_i[o,e] = sum_d W_i[o,d]*ef[e,d] (MFMA); acc[o,e] += x[src[e],i]*D_i.
// Wave w owns o-slice [16w,16w+16). ef frags in regs; W streamed from L2
// with register double-buffer. Epilogue: +NB[src], atomicAdd to aggr[dst].
__global__ __launch_bounds__(256, 4) void msg_fused(
    const unsigned short* __restrict__ ef_b,   // [E][64] bf16
    const unsigned short* __restrict__ wb,     // [64][64][64] bf16 (i,o,d); +1 slice pad
    const float* __restrict__ x,               // [N][64] f32
    const float* __restrict__ NB,              // [N][64] f32
    const int* __restrict__ src,
    const int* __restrict__ dst,
    float* __restrict__ aggr) {                // [N][64] f32
    __shared__ float xT[64][64];               // xT[i][e_local] = x[src[e]][i]
    const int tid = threadIdx.x;
    const int e0 = blockIdx.x * 64;

    // gather x rows of the 64 src nodes, transposed (f32, exact)
#pragma unroll
    for (int it = 0; it < 4; ++it) {
        int f = it * 256 + tid;
        int e = f & 63, c = f >> 6;            // c in 0..15
        int s = src[e0 + e];
        const f32x4 xv = *reinterpret_cast<const f32x4*>(x + (size_t)s * 64 + c * 4);
        xT[4 * c + 0][e] = xv.x;
        xT[4 * c + 1][e] = xv.y;
        xT[4 * c + 2][e] = xv.z;
        xT[4 * c + 3][e] = xv.w;
    }

    const int w = tid >> 6, l = tid & 63, lg = l >> 4, ln = l & 15;

    // ef B-frags: tile t = edges e0+16t+ln (column operand, held in regs)
    bf16x8 B0[4], B1[4];
#pragma unroll
    for (int t = 0; t < 4; ++t) {
        const unsigned short* pe = ef_b + (size_t)(e0 + 16 * t + ln) * 64 + 8 * lg;
        B0[t] = *reinterpret_cast<const bf16x8*>(pe);
        B1[t] = *reinterpret_cast<const bf16x8*>(pe + 32);
    }

    // W A-frag: row o = 16w+ln of slice i (this wave's o-slice)
    const unsigned short* pw = wb + (size_t)(16 * w + ln) * 64 + 8 * lg;
    bf16x8 Ac0 = *reinterpret_cast<const bf16x8*>(pw);
    bf16x8 Ac1 = *reinterpret_cast<const bf16x8*>(pw + 32);

    __syncthreads();

    f32x4 acc0 = {}, acc1 = {}, acc2 = {}, acc3 = {};
#pragma unroll 2
    for (int i = 0; i < 64; ++i) {
        const unsigned short* pn = pw + (size_t)(i + 1) * 4096;
        const bf16x8 An0 = *reinterpret_cast<const bf16x8*>(pn);
        const bf16x8 An1 = *reinterpret_cast<const bf16x8*>(pn + 32);
        const float xs0 = xT[i][ln];
        const float xs1 = xT[i][16 + ln];
        const float xs2 = xT[i][32 + ln];
        const float xs3 = xT[i][48 + ln];
        f32x4 c0 = {}, c1 = {}, c2 = {}, c3 = {};
        c0 = __builtin_amdgcn_mfma_f32_16x16x32_bf16(Ac0, B0[0], c0, 0, 0, 0);
        c1 = __builtin_amdgcn_mfma_f32_16x16x32_bf16(Ac0, B0[1], c1, 0, 0, 0);
        c2 = __builtin_amdgcn_mfma_f32_16x16x32_bf16(Ac0, B0[2], c2, 0, 0, 0);
        c3 = __builtin_amdgcn_mfma_f32_16x16x32_bf16(Ac0, B0[3], c3, 0, 0, 0);
        c0 = __builtin_amdgcn_mfma_f32_16x16x32_bf16(Ac1, B1[0], c0, 0, 0, 0);
        c1 = __builtin_amdgcn_mfma_f32_16x16x32_bf16(Ac1, B1[1], c1, 0, 0, 0);
        c2 = __builtin_amdgcn_mfma_f32_16x16x32_bf16(Ac1, B1[2], c2, 0, 0, 0);
        c3 = __builtin_amdgcn_mfma_f32_16x16x32_bf16(Ac1, B1[3], c3, 0, 0, 0);
        acc0 += xs0 * c0;
        acc1 += xs1 * c1;
        acc2 += xs2 * c2;
        acc3 += xs3 * c3;
        Ac0 = An0; Ac1 = An1;
    }

    // epilogue: add NB[src], scatter to aggr[dst]
    f32x4 accs[4] = {acc0, acc1, acc2, acc3};
#pragma unroll
    for (int t = 0; t < 4; ++t) {
        const int e = e0 + 16 * t + ln;
        const int s = src[e], d = dst[e];
        const f32x4 nb = *reinterpret_cast<const f32x4*>(NB + (size_t)s * 64 + 16 * w + 4 * lg);
#pragma unroll
        for (int rr = 0; rr < 4; ++rr)
            atomicAdd(aggr + (size_t)d * 64 + 16 * w + 4 * lg + rr, accs[t][rr] + nb[rr]);
    }
}

// ---- BN statistics ----
__global__ __launch_bounds__(256) void bn_stats(const float* __restrict__ h,
                                                float* __restrict__ sums) {
    const int tid = threadIdx.x;
    const int o = tid & 63, g = tid >> 6;
    const int n0 = blockIdx.x * 128;
    float s = 0.f, s2 = 0.f;
    for (int k = 0; k < 32; ++k) {
        float v = h[(size_t)(n0 + g * 32 + k) * 64 + o];
        s += v; s2 += v * v;
    }
    __shared__ float red[2][4][64];
    red[0][g][o] = s; red[1][g][o] = s2;
    __syncthreads();
    if (g == 0) {
        s  = red[0][0][o] + red[0][1][o] + red[0][2][o] + red[0][3][o];
        s2 = red[1][0][o] + red[1][1][o] + red[1][2][o] + red[1][3][o];
        atomicAdd(&sums[o], s);
        atomicAdd(&sums[64 + o], s2);
    }
}

__global__ void bn_finalize(const float* __restrict__ sums,
                            const float* __restrict__ gamma,
                            const float* __restrict__ beta,
                            float* __restrict__ ss, float invN) {
    const int o = threadIdx.x;   // 64 threads
    float mean = sums[o] * invN;
    float var = sums[64 + o] * invN - mean * mean;
    float sc = gamma[o] * rsqrtf(var + BN_EPS);
    ss[o] = sc;
    ss[64 + o] = beta[o] - mean * sc;
}

// ---- BN apply + LeakyReLU (f32) ----
__global__ __launch_bounds__(256) void bn_apply(const float* __restrict__ h,
                                                const float* __restrict__ ss,
                                                float* __restrict__ outf, int total4) {
    const int idx = blockIdx.x * 256 + threadIdx.x;
    if (idx >= total4) return;
    const f32x4 v = *reinterpret_cast<const f32x4*>(h + (size_t)idx * 4);
    const int o0 = (idx * 4) & 63;
    const f32x4 sc = *reinterpret_cast<const f32x4*>(ss + o0);
    const f32x4 sh = *reinterpret_cast<const f32x4*>(ss + 64 + o0);
    f32x4 r = v * sc + sh;
    f32x4 res;
    res.x = fmaxf(r.x, 0.f) + NEG_SLOPE * fminf(r.x, 0.f);
    res.y = fmaxf(r.y, 0.f) + NEG_SLOPE * fminf(r.y, 0.f);
    res.z = fmaxf(r.z, 0.f) + NEG_SLOPE * fminf(r.z, 0.f);
    res.w = fmaxf(r.w, 0.f) + NEG_SLOPE * fminf(r.w, 0.f);
    *reinterpret_cast<f32x4*>(outf + (size_t)idx * 4) = res;
}

// ---- final: out[n,q] = sum_o x[n,o]*W_lin[q,o] + b_lin[q] ----
__global__ __launch_bounds__(256) void out_kernel(const float* __restrict__ x2,
                                                  const float* __restrict__ Wl,
                                                  const float* __restrict__ bl,
                                                  float* __restrict__ out) {
    __shared__ float Wt[64][129];
    __shared__ float xl[64][64];
    const int tid = threadIdx.x;
    const int n0 = blockIdx.x * 64;
    for (int f = tid; f < 8192; f += 256) {
        int q = f >> 6, o = f & 63;
        Wt[o][q] = Wl[f];
    }
    for (int f = tid; f < 1024; f += 256) {
        int r = f >> 4, c = f & 15;
        *reinterpret_cast<float4*>(&xl[r][c * 4]) =
            *reinterpret_cast<const float4*>(x2 + (size_t)(n0 + r) * 64 + c * 4);
    }
    __syncthreads();
    const int q = tid & 127, ng = tid >> 7;
    float acc[32] = {};
    for (int o4 = 0; o4 < 16; ++o4) {
        float w0 = Wt[4 * o4 + 0][q], w1 = Wt[4 * o4 + 1][q];
        float w2 = Wt[4 * o4 + 2][q], w3 = Wt[4 * o4 + 3][q];
#pragma unroll
        for (int k = 0; k < 32; ++k) {
            const f32x4 xv = *reinterpret_cast<const f32x4*>(&xl[ng + 2 * k][4 * o4]);
            acc[k] += xv.x * w0 + xv.y * w1 + xv.z * w2 + xv.w * w3;
        }
    }
    const float b = bl[q];
#pragma unroll
    for (int k = 0; k < 32; ++k)
        out[(size_t)(n0 + ng + 2 * k) * 128 + q] = acc[k] + b;
}

extern "C" void kernel_launch(void* const* d_in, const int* in_sizes, int n_in,
                              void* d_out, int out_size, void* d_ws, size_t ws_size,
                              hipStream_t stream) {
    const float* nf      = (const float*)d_in[0];
    const int*   ei      = (const int*)d_in[1];
    const float* ef      = (const float*)d_in[2];
    const float* W_edge0 = (const float*)d_in[4];
    const float* b_edge0 = (const float*)d_in[5];
    const float* W_root0 = (const float*)d_in[6];
    const float* b_root0 = (const float*)d_in[7];
    const float* gamma0  = (const float*)d_in[8];
    const float* beta0   = (const float*)d_in[9];
    const float* W_edge1 = (const float*)d_in[10];
    const float* b_edge1 = (const float*)d_in[11];
    const float* W_root1 = (const float*)d_in[12];
    const float* b_root1 = (const float*)d_in[13];
    const float* gamma1  = (const float*)d_in[14];
    const float* beta1   = (const float*)d_in[15];
    const float* W_lin   = (const float*)d_in[16];
    const float* b_lin   = (const float*)d_in[17];

    const int N = in_sizes[0] / 64;   // 8192
    const int E = in_sizes[1] / 2;    // 32768
    const int* src = ei;
    const int* dst = ei + E;

    unsigned short* ef_b = (unsigned short*)d_ws;          // E*64
    unsigned short* wb0  = ef_b + (size_t)E * 64;          // 64*64*64
    unsigned short* wb1  = wb0 + 262144;                   // 64*64*64
    unsigned short* pad  = wb1 + 262144;                   // 4096 (prefetch overrun pad)
    float* aggr  = (float*)(pad + 4096);                   // N*64
    float* NBbuf = aggr + (size_t)N * 64;                  // N*64
    float* x1    = NBbuf + (size_t)N * 64;                 // N*64
    float* x2    = x1 + (size_t)N * 64;                    // N*64
    float* stats = x2 + (size_t)N * 64;                    // 256
    float* ssbuf = stats + 256;                            // 256

    const float invN = 1.0f / (float)N;
    const int na4 = E * 64 / 4;          // 524288
    const int nw4 = 262144 / 4;          // 65536
    const int nb4 = N * 64 / 4;          // 131072

    cvt3<<<(na4 + 2 * nw4) / 256, 256, 0, stream>>>(ef, na4, W_edge0, nw4, W_edge1, nw4,
                                                    ef_b, wb0, wb1);
    hipMemsetAsync(stats, 0, 256 * sizeof(float), stream);

    // ---- layer 0 ----
    node_mm2<<<dim3(N / 64, 2), 256, 0, stream>>>(nf, W_root0, b_root0, aggr, b_edge0, NBbuf);
    msg_fused<<<E / 64, 256, 0, stream>>>(ef_b, wb0, nf, NBbuf, src, dst, aggr);
    bn_stats<<<N / 128, 256, 0, stream>>>(aggr, stats);
    bn_finalize<<<1, 64, 0, stream>>>(stats, gamma0, beta0, ssbuf, invN);
    bn_apply<<<(nb4 + 255) / 256, 256, 0, stream>>>(aggr, ssbuf, x1, nb4);

    // ---- layer 1 ----
    node_mm2<<<dim3(N / 64, 2), 256, 0, stream>>>(x1, W_root1, b_root1, aggr, b_edge1, NBbuf);
    msg_fused<<<E / 64, 256, 0, stream>>>(ef_b, wb1, x1, NBbuf, src, dst, aggr);
    bn_stats<<<N / 128, 256, 0, stream>>>(aggr, stats + 128);
    bn_finalize<<<1, 64, 0, stream>>>(stats + 128, gamma1, beta1, ssbuf + 128, invN);
    bn_apply<<<(nb4 + 255) / 256, 256, 0, stream>>>(aggr, ssbuf + 128, x2, nb4);

    // ---- final linear ----
    out_kernel<<<N / 64, 256, 0, stream>>>(x2, W_lin, b_lin, (float*)d_out);
}